// Round 13
// baseline (150.437 us; speedup 1.0000x reference)
//
#include <hip/hip_runtime.h>
#include <hip/hip_bf16.h>
#include <stdint.h>

#define N_ROWS 8192
#define DIM    768          // elements per row; == BYTES per row in int8
#define BM     256
#define BN     256
#define BKB    128          // K-tile bytes (= i8 elements)
#define KTILES (DIM / BKB)  // 6
#define NT2    (N_ROWS / BN)
#define LDS_BYTES 65536

typedef __attribute__((ext_vector_type(4)))  int   i32x4;
typedef __attribute__((ext_vector_type(4)))  float f32x4;

__device__ __forceinline__ float tstudent(float c) {
    // (1 + 0.5*(1-c))^{-1.5} = t^{-1.5}, t = 1.5 - 0.5c
    float t = 1.5f - 0.5f * c;
    float r = rsqrtf(t);
    return r * r * r;
}

// ---------------- kernel 1: row L2-normalize fp32 -> int8, fp32 diag numerator, post-quant inv-norms ----------------
__global__ __launch_bounds__(256) void norm_kernel(const float* __restrict__ z1,
                                                   const float* __restrict__ z2,
                                                   signed char* __restrict__ n1,
                                                   signed char* __restrict__ n2,
                                                   float* __restrict__ num,
                                                   float* __restrict__ inva,
                                                   float* __restrict__ invb) {
    int row = blockIdx.x;
    int t = threadIdx.x;
    const float* s1 = z1 + (size_t)row * DIM;
    const float* s2 = z2 + (size_t)row * DIM;
    float a0 = s1[t], a1 = s1[t + 256], a2 = s1[t + 512];
    float b0 = s2[t], b1 = s2[t + 256], b2 = s2[t + 512];
    float ss1 = a0 * a0 + a1 * a1 + a2 * a2;
    float ss2 = b0 * b0 + b1 * b1 + b2 * b2;
    float sd  = a0 * b0 + a1 * b1 + a2 * b2;
    for (int off = 32; off; off >>= 1) {
        ss1 += __shfl_down(ss1, off);
        ss2 += __shfl_down(ss2, off);
        sd  += __shfl_down(sd, off);
    }
    __shared__ float w1[4], w2[4], wd[4];
    __shared__ float sc1_s, sc2_s;
    if ((t & 63) == 0) { int wi = t >> 6; w1[wi] = ss1; w2[wi] = ss2; wd[wi] = sd; }
    __syncthreads();
    if (t == 0) {
        float nrm1 = fmaxf(sqrtf(w1[0] + w1[1] + w1[2] + w1[3]), 1e-8f);
        float nrm2 = fmaxf(sqrtf(w2[0] + w2[1] + w2[2] + w2[3]), 1e-8f);
        float dot  = wd[0] + wd[1] + wd[2] + wd[3];
        sc1_s = 127.0f / nrm1;
        sc2_s = 127.0f / nrm2;
        num[row] = tstudent(dot / (nrm1 * nrm2));   // numerator exact in fp32
    }
    __syncthreads();
    float sc1 = sc1_s, sc2 = sc2_s;
    float qa0 = fminf(fmaxf(rintf(a0 * sc1), -127.f), 127.f);
    float qa1 = fminf(fmaxf(rintf(a1 * sc1), -127.f), 127.f);
    float qa2 = fminf(fmaxf(rintf(a2 * sc1), -127.f), 127.f);
    float qb0 = fminf(fmaxf(rintf(b0 * sc2), -127.f), 127.f);
    float qb1 = fminf(fmaxf(rintf(b1 * sc2), -127.f), 127.f);
    float qb2 = fminf(fmaxf(rintf(b2 * sc2), -127.f), 127.f);
    signed char* d1 = n1 + (size_t)row * DIM;
    signed char* d2 = n2 + (size_t)row * DIM;
    d1[t]       = (signed char)(int)qa0;
    d1[t + 256] = (signed char)(int)qa1;
    d1[t + 512] = (signed char)(int)qa2;
    d2[t]       = (signed char)(int)qb0;
    d2[t + 256] = (signed char)(int)qb1;
    d2[t + 512] = (signed char)(int)qb2;
    float sq1 = qa0 * qa0 + qa1 * qa1 + qa2 * qa2;
    float sq2 = qb0 * qb0 + qb1 * qb1 + qb2 * qb2;
    for (int off = 32; off; off >>= 1) {
        sq1 += __shfl_down(sq1, off);
        sq2 += __shfl_down(sq2, off);
    }
    __shared__ float wq1[4], wq2[4];
    if ((t & 63) == 0) { int wi = t >> 6; wq1[wi] = sq1; wq2[wi] = sq2; }
    __syncthreads();
    if (t == 0) {
        inva[row] = rsqrtf(wq1[0] + wq1[1] + wq1[2] + wq1[3]);
        invb[row] = rsqrtf(wq2[0] + wq2[1] + wq2[2] + wq2[3]);
    }
}

// ---------------- kernel 2: 256x256 16-wave int8 MFMA GEMM — A from global (L1/L2), B via LDS ----------------
// R13 change vs R12: A-fragments are loaded DIRECTLY from global memory (no LDS staging,
// no swizzle on A). Geometry makes them perfectly 64B-line coalesced: lanes (l, l+16,
// l+32, l+48) read row rowbase+wr*64+m*16+(l&15) at bytes kt*128+ks*64+(l>>4)*16 ->
// 16 aligned 64-B lines per instruction. A tile (32 KB) is L1/L2-resident thanks to the
// XCD supertile, so the 4x wc-redundancy is served by caches instead of the LDS port.
// LDS now holds only B (2 x 32 KB double buffer): read traffic halves; B staging,
// swizzle (slot = granule ^ (row&7)), read geometry, and the per-tile VMW(0)+BAR
// publish are IDENTICAL to R12's proven form. MFMA becomes the binding pipe.

__device__ __forceinline__ void stG(const signed char* g, char* lds, int t, int j) {
    __builtin_amdgcn_global_load_lds(
        (const __attribute__((address_space(1))) void*)(g + (size_t)j * 128 * DIM),
        (__attribute__((address_space(3))) void*)(lds + t * 16 + j * 16384), 16, 0, 0);
}

#define BAR()  asm volatile("s_barrier" ::: "memory")
#define VMW(n) asm volatile("s_waitcnt vmcnt(" #n ")" ::: "memory")

// One k-half (64 k-bytes): 4 B-frags from LDS at SEG, 4 A-frags from global at
// kt*128 + KS*64 (compiler schedules the loads together; deps auto-waited).
#define HALFK(SEG, GOFF)                                                        \
    {                                                                           \
        i32x4 b0 = *(const i32x4*)(Bb + rbB + 0 * 2048 + (SEG));                \
        i32x4 b1 = *(const i32x4*)(Bb + rbB + 1 * 2048 + (SEG));                \
        i32x4 b2 = *(const i32x4*)(Bb + rbB + 2 * 2048 + (SEG));                \
        i32x4 b3 = *(const i32x4*)(Bb + rbB + 3 * 2048 + (SEG));                \
        i32x4 a0 = *(const i32x4*)(Aw + (GOFF));                                \
        i32x4 a1 = *(const i32x4*)(Aw + 12288 + (GOFF));                        \
        i32x4 a2 = *(const i32x4*)(Aw + 24576 + (GOFF));                        \
        i32x4 a3 = *(const i32x4*)(Aw + 36864 + (GOFF));                        \
        __builtin_amdgcn_s_setprio(1);                                          \
        acc[0][0] = __builtin_amdgcn_mfma_i32_16x16x64_i8(a0, b0, acc[0][0], 0, 0, 0); \
        acc[0][1] = __builtin_amdgcn_mfma_i32_16x16x64_i8(a0, b1, acc[0][1], 0, 0, 0); \
        acc[0][2] = __builtin_amdgcn_mfma_i32_16x16x64_i8(a0, b2, acc[0][2], 0, 0, 0); \
        acc[0][3] = __builtin_amdgcn_mfma_i32_16x16x64_i8(a0, b3, acc[0][3], 0, 0, 0); \
        acc[1][0] = __builtin_amdgcn_mfma_i32_16x16x64_i8(a1, b0, acc[1][0], 0, 0, 0); \
        acc[1][1] = __builtin_amdgcn_mfma_i32_16x16x64_i8(a1, b1, acc[1][1], 0, 0, 0); \
        acc[1][2] = __builtin_amdgcn_mfma_i32_16x16x64_i8(a1, b2, acc[1][2], 0, 0, 0); \
        acc[1][3] = __builtin_amdgcn_mfma_i32_16x16x64_i8(a1, b3, acc[1][3], 0, 0, 0); \
        acc[2][0] = __builtin_amdgcn_mfma_i32_16x16x64_i8(a2, b0, acc[2][0], 0, 0, 0); \
        acc[2][1] = __builtin_amdgcn_mfma_i32_16x16x64_i8(a2, b1, acc[2][1], 0, 0, 0); \
        acc[2][2] = __builtin_amdgcn_mfma_i32_16x16x64_i8(a2, b2, acc[2][2], 0, 0, 0); \
        acc[2][3] = __builtin_amdgcn_mfma_i32_16x16x64_i8(a2, b3, acc[2][3], 0, 0, 0); \
        acc[3][0] = __builtin_amdgcn_mfma_i32_16x16x64_i8(a3, b0, acc[3][0], 0, 0, 0); \
        acc[3][1] = __builtin_amdgcn_mfma_i32_16x16x64_i8(a3, b1, acc[3][1], 0, 0, 0); \
        acc[3][2] = __builtin_amdgcn_mfma_i32_16x16x64_i8(a3, b2, acc[3][2], 0, 0, 0); \
        acc[3][3] = __builtin_amdgcn_mfma_i32_16x16x64_i8(a3, b3, acc[3][3], 0, 0, 0); \
        __builtin_amdgcn_s_setprio(0);                                          \
    }

__global__ __launch_bounds__(1024) void gemm_kernel(const signed char* __restrict__ n1,
                                                    const signed char* __restrict__ n2,
                                                    const float* __restrict__ inva,
                                                    const float* __restrict__ invb,
                                                    float* __restrict__ partial) {
    extern __shared__ char smem[];   // [B buf0 32K][B buf1 32K]
    int t = threadIdx.x;
    int l = t & 63;
    int w = t >> 6;    // 0..15
    int wr = w >> 2;   // 0..3 -> A 64-row band
    int wc = w & 3;    // 0..3 -> B 64-col band

    // XCD-aware + L2 supertile mapping (1024 blocks, bijective)
    int bid = blockIdx.x;
    int xcd = bid & 7, idx = bid >> 3;
    int br = xcd * 4 + (idx & 3);
    int bc = (idx >> 4) * 4 + ((idx >> 2) & 3);
    int rowbase = br * BM, colbase = bc * BN;

    // B staging: thread t covers LDS row sr = t>>3 (+128j), granule t&7;
    // inverse-swizzled global 16B-granule = (t&7) ^ (sr&7)
    int sr = t >> 3;
    int gcol0 = ((t & 7) ^ (sr & 7)) * 16;
    const signed char* Bg = n2 + (size_t)(colbase + sr) * DIM + gcol0;

    // A direct-from-global base: row = rowbase + wr*64 + (l&15), k-byte = (l>>4)*16
    const signed char* Aw = n1 + (size_t)(rowbase + wr * 64 + (l & 15)) * DIM + (l >> 4) * 16;

    i32x4 acc[4][4] = {};   // 64 regs (AGPR)

    // B read side: frag row r = l&15 (bands multiples of 64 -> r&7 = l&7),
    // true granule = (l>>4) + 4*ks, slot = granule ^ (l&7)
    int seg0 = (((l >> 4) + 0) ^ (l & 7)) * 16;
    int seg1 = (((l >> 4) + 4) ^ (l & 7)) * 16;
    int rbB = (wc * 64 + (l & 15)) * 128;

    // prologue: stage B K-tile 0 into parity 0
    stG(Bg, smem, t, 0); stG(Bg, smem, t, 1);
    VMW(0); BAR();

    #pragma unroll
    for (int kt = 0; kt < KTILES - 1; ++kt) {
        int db = kt & 1;
        const char* Bb = smem + db * 32768;
        char* BnW = smem + (db ^ 1) * 32768;
        const signed char* Bgn = Bg + (kt + 1) * BKB;

        // stage next B tile first (oldest in vmcnt queue), then compute both k-halves
        stG(Bgn, BnW, t, 0); stG(Bgn, BnW, t, 1);
        HALFK(seg0, kt * 128);
        HALFK(seg1, kt * 128 + 64);
        VMW(0); BAR();   // stage drain distance = full tile of compute >> L2 latency
    }
    {   // peeled last tile (kt = 5, parity 1): no staging
        const char* Bb = smem + 32768;
        HALFK(seg0, 5 * 128);
        HALFK(seg1, 5 * 128 + 64);
    }

    // ---------------- epilogue: cos = acc * inva[row] * invb[col]; t-Student + row sums ----------------
    // C/D map: row = wr*64 + m*16 + (l>>4)*4 + j (A-side), col = wc*64 + n*16 + (l&15)
    float invb_n[4];
    #pragma unroll
    for (int n = 0; n < 4; ++n)
        invb_n[n] = invb[colbase + wc * 64 + n * 16 + (l & 15)];

    float* red = (float*)smem;  // 256 rows x 4 wc
    __syncthreads();
    #pragma unroll
    for (int m = 0; m < 4; ++m) {
        f32x4 ia = *(const f32x4*)(inva + rowbase + wr * 64 + m * 16 + (l >> 4) * 4);
        #pragma unroll
        for (int j = 0; j < 4; ++j) {
            float s = 0.f;
            #pragma unroll
            for (int n = 0; n < 4; ++n) {
                float cos = (float)acc[m][n][j] * ia[j] * invb_n[n];
                s += tstudent(cos);
            }
            s += __shfl_xor(s, 1);
            s += __shfl_xor(s, 2);
            s += __shfl_xor(s, 4);
            s += __shfl_xor(s, 8);
            if ((l & 15) == 0) {
                int row = wr * 64 + m * 16 + (l >> 4) * 4 + j;
                red[row * 4 + wc] = s;
            }
        }
    }
    __syncthreads();
    if (t < BM) {
        partial[(size_t)bc * N_ROWS + rowbase + t] = red[t * 4 + 0] + red[t * 4 + 1] + red[t * 4 + 2] + red[t * 4 + 3];
    }
}

// ---------------- kernel 3: per-row denom + ratio, per-block sums ----------------
__global__ __launch_bounds__(256) void reduce_kernel(const float* __restrict__ partial,
                                                     const float* __restrict__ num,
                                                     float* __restrict__ blocksum) {
    int row = blockIdx.x * 256 + threadIdx.x;
    float d = 0.f;
    #pragma unroll 8
    for (int ct = 0; ct < NT2; ++ct) d += partial[(size_t)ct * N_ROWS + row];
    float s = num[row] / d;
    for (int off = 32; off; off >>= 1) s += __shfl_down(s, off);
    __shared__ float wsum[4];
    if ((threadIdx.x & 63) == 0) wsum[threadIdx.x >> 6] = s;
    __syncthreads();
    if (threadIdx.x == 0) blocksum[blockIdx.x] = wsum[0] + wsum[1] + wsum[2] + wsum[3];
}

// ---------------- kernel 4: final scalar ----------------
__global__ __launch_bounds__(64) void final_kernel(const float* __restrict__ blocksum,
                                                   float* __restrict__ out) {
    int l = threadIdx.x;
    float s = (l < 32) ? blocksum[l] : 0.f;
    for (int off = 32; off; off >>= 1) s += __shfl_down(s, off);
    if (l == 0) out[0] = -(s / (float)N_ROWS);
}

extern "C" void kernel_launch(void* const* d_in, const int* in_sizes, int n_in,
                              void* d_out, int out_size, void* d_ws, size_t ws_size,
                              hipStream_t stream) {
    const float* z1 = (const float*)d_in[0];
    const float* z2 = (const float*)d_in[1];
    char* ws = (char*)d_ws;
    const size_t n_bytes = (size_t)N_ROWS * DIM;   // 6,291,456 (int8)
    signed char* n1 = (signed char*)ws;
    signed char* n2 = (signed char*)(ws + n_bytes);
    size_t base2 = 2 * n_bytes;
    float* num      = (float*)(ws + base2);                    // 32 KB
    float* inva     = (float*)(ws + base2 + 32768);            // 32 KB
    float* invb     = (float*)(ws + base2 + 65536);            // 32 KB
    float* partial  = (float*)(ws + base2 + 98304);            // 1 MB used
    float* blocksum = (float*)(ws + base2 + 98304 + 2097152);  // 128 B

    hipFuncSetAttribute((const void*)gemm_kernel,
                        hipFuncAttributeMaxDynamicSharedMemorySize, LDS_BYTES);

    norm_kernel<<<N_ROWS, 256, 0, stream>>>(z1, z2, n1, n2, num, inva, invb);
    gemm_kernel<<<NT2 * NT2, 1024, LDS_BYTES, stream>>>(n1, n2, inva, invb, partial);
    reduce_kernel<<<N_ROWS / 256, 256, 0, stream>>>(partial, num, blocksum);
    final_kernel<<<1, 64, 0, stream>>>(blocksum, (float*)d_out);
}